// Round 1
// baseline (284.278 us; speedup 1.0000x reference)
//
#include <hip/hip_runtime.h>
#include <math.h>

#define N_BINS 15
#define NUM_CLASSES 128

// Pass 1: one wave (64 lanes) per row. Each lane loads float2 (8B) -> 512B/row
// coalesced. Wave-reduce (max, argmax) with first-occurrence tie-break, then
// wave-reduce sum(exp(l - max)). conf = 1/sumexp. Histogram into LDS, flush
// per-block to global atomics (f64 for sums -> atomic-order noise is ~0).
__global__ __launch_bounds__(256) void ece_pass1(
    const float* __restrict__ logits,
    const int* __restrict__ labels,
    int n,
    double* __restrict__ conf_sum,
    double* __restrict__ acc_sum,
    unsigned int* __restrict__ counts)
{
    __shared__ float s_conf[N_BINS];
    __shared__ float s_acc[N_BINS];
    __shared__ unsigned int s_cnt[N_BINS];

    const int t = threadIdx.x;
    if (t < N_BINS) { s_conf[t] = 0.f; s_acc[t] = 0.f; s_cnt[t] = 0u; }
    __syncthreads();

    const int lane = t & 63;
    const int wave = t >> 6;
    const int wavesPerBlock = blockDim.x >> 6;

    long long row = (long long)blockIdx.x * wavesPerBlock + wave;
    const long long rstride = (long long)gridDim.x * wavesPerBlock;

    for (; row < n; row += rstride) {
        const float2* __restrict__ p =
            (const float2*)(logits + row * (long long)NUM_CLASSES);
        const float2 v = p[lane];

        // local max + index (first-occurrence tie-break: x wins on equal)
        float m;
        int mi;
        if (v.x >= v.y) { m = v.x; mi = lane * 2; }
        else            { m = v.y; mi = lane * 2 + 1; }

        // wave butterfly reduce for (max, argmax), smaller index wins ties
        #pragma unroll
        for (int off = 32; off > 0; off >>= 1) {
            float om = __shfl_xor(m, off, 64);
            int   oi = __shfl_xor(mi, off, 64);
            if (om > m || (om == m && oi < mi)) { m = om; mi = oi; }
        }

        // sum of exp(l - max); the max element contributes exactly 1
        float s = __expf(v.x - m) + __expf(v.y - m);
        #pragma unroll
        for (int off = 32; off > 0; off >>= 1)
            s += __shfl_xor(s, off, 64);

        if (lane == 0) {
            const float conf = 1.0f / s;
            int bin = (int)ceilf(conf * (float)N_BINS) - 1;
            bin = min(max(bin, 0), N_BINS - 1);
            const float acc = (mi == labels[row]) ? 1.0f : 0.0f;
            atomicAdd(&s_conf[bin], conf);
            atomicAdd(&s_acc[bin], acc);
            atomicAdd(&s_cnt[bin], 1u);
        }
    }

    __syncthreads();
    if (t < N_BINS && s_cnt[t] != 0u) {
        atomicAdd(&conf_sum[t], (double)s_conf[t]);
        atomicAdd(&acc_sum[t], (double)s_acc[t]);
        atomicAdd(&counts[t], s_cnt[t]);
    }
}

// Pass 2: tiny scalar finish in f64.
__global__ void ece_pass2(const double* __restrict__ conf_sum,
                          const double* __restrict__ acc_sum,
                          const unsigned int* __restrict__ counts,
                          int n, float* __restrict__ out)
{
    double ece = 0.0;
    #pragma unroll
    for (int b = 0; b < N_BINS; ++b) {
        const unsigned int c = counts[b];
        if (c != 0u) {
            const double cd = (double)c;
            const double gap = fabs(conf_sum[b] / cd - acc_sum[b] / cd);
            ece += gap * cd / (double)n;
        }
    }
    out[0] = (float)ece;
}

extern "C" void kernel_launch(void* const* d_in, const int* in_sizes, int n_in,
                              void* d_out, int out_size, void* d_ws, size_t ws_size,
                              hipStream_t stream)
{
    const float* logits = (const float*)d_in[0];
    const int*   labels = (const int*)d_in[1];
    const int n = in_sizes[1];  // 1,000,000 rows

    double* conf_sum = (double*)d_ws;
    double* acc_sum  = conf_sum + N_BINS;
    unsigned int* counts = (unsigned int*)(acc_sum + N_BINS);

    // d_ws is poisoned 0xAA and NOT re-poisoned between replays: zero it
    // ourselves every call (async memset is graph-capture safe).
    hipMemsetAsync(d_ws, 0, N_BINS * (sizeof(double) * 2 + sizeof(unsigned int)),
                   stream);

    const int blocks = 2048;   // 4 waves/block -> ~122 rows per wave, amortizes launch
    ece_pass1<<<blocks, 256, 0, stream>>>(logits, labels, n,
                                          conf_sum, acc_sum, counts);
    ece_pass2<<<1, 1, 0, stream>>>(conf_sum, acc_sum, counts, n, (float*)d_out);
}

// Round 2
// 146.176 us; speedup vs baseline: 1.9448x; 1.9448x over previous
//
#include <hip/hip_runtime.h>
#include <math.h>

#define N_BINS 15
#define NUM_CLASSES 128

// Pass 1: 16 lanes per row, 4 rows per wave. Each lane loads 2x float4
// (cols 4s..4s+3 and 64+4s..64+4s+3) -> each load instruction covers a
// contiguous 256B half-row per 16-lane group (perfect coalescing).
// Width-16 butterflies (4 steps) reduce (max,argmax) then sum(exp(l-max));
// one wave-wide shuffle instruction serves 4 rows simultaneously.
// Next grid-stride tile is prefetched before the current compute to keep
// multiple loads in flight (latency was the round-1 limiter, not BW).
__global__ __launch_bounds__(256) void ece_pass1(
    const float* __restrict__ logits,
    const int* __restrict__ labels,
    int n,
    double* __restrict__ conf_sum,
    double* __restrict__ acc_sum,
    unsigned int* __restrict__ counts)
{
    __shared__ float s_conf[N_BINS];
    __shared__ float s_acc[N_BINS];
    __shared__ unsigned int s_cnt[N_BINS];

    const int t = threadIdx.x;
    if (t < N_BINS) { s_conf[t] = 0.f; s_acc[t] = 0.f; s_cnt[t] = 0u; }
    __syncthreads();

    const int lane = t & 63;
    const int g    = lane >> 4;   // row-group within wave (0..3)
    const int s    = lane & 15;   // sublane within group
    const int wavesPerBlock = blockDim.x >> 6;
    const long long waveId = (long long)blockIdx.x * wavesPerBlock + (t >> 6);
    const long long nWaves = (long long)gridDim.x * wavesPerBlock;

    long long row0 = waveId * 4;
    const long long rstride = nWaves * 4;

    // prologue prefetch
    float4 a, b;
    {
        const long long r = row0 + g;
        if (r < n) {
            const float4* __restrict__ p =
                (const float4*)(logits + r * (long long)NUM_CLASSES);
            a = p[s];
            b = p[s + 16];
        }
    }

    for (; row0 < n; row0 += rstride) {
        const float4 ca = a, cb = b;
        const long long crow = row0 + g;

        // prefetch next tile (independent of current compute)
        {
            const long long nr = row0 + rstride + g;
            if (nr < n) {
                const float4* __restrict__ p =
                    (const float4*)(logits + nr * (long long)NUM_CLASSES);
                a = p[s];
                b = p[s + 16];
            }
        }

        // local max + argmax among 8 elems (column order => strict '>' gives
        // first occurrence)
        float m = ca.x; int mi = 4 * s;
        if (ca.y > m) { m = ca.y; mi = 4 * s + 1; }
        if (ca.z > m) { m = ca.z; mi = 4 * s + 2; }
        if (ca.w > m) { m = ca.w; mi = 4 * s + 3; }
        if (cb.x > m) { m = cb.x; mi = 64 + 4 * s; }
        if (cb.y > m) { m = cb.y; mi = 64 + 4 * s + 1; }
        if (cb.z > m) { m = cb.z; mi = 64 + 4 * s + 2; }
        if (cb.w > m) { m = cb.w; mi = 64 + 4 * s + 3; }

        // width-16 butterfly for (max, argmax); smaller column wins ties
        #pragma unroll
        for (int off = 8; off > 0; off >>= 1) {
            const float om = __shfl_xor(m, off, 16);
            const int   oi = __shfl_xor(mi, off, 16);
            if (om > m || (om == m && oi < mi)) { m = om; mi = oi; }
        }

        // sum of exp(l - max); max element contributes exactly 1
        float e = __expf(ca.x - m) + __expf(ca.y - m)
                + __expf(ca.z - m) + __expf(ca.w - m)
                + __expf(cb.x - m) + __expf(cb.y - m)
                + __expf(cb.z - m) + __expf(cb.w - m);
        #pragma unroll
        for (int off = 8; off > 0; off >>= 1)
            e += __shfl_xor(e, off, 16);

        if (s == 0 && crow < n) {
            const float conf = 1.0f / e;
            int bin = (int)ceilf(conf * (float)N_BINS) - 1;
            bin = min(max(bin, 0), N_BINS - 1);
            const float acc = (mi == labels[crow]) ? 1.0f : 0.0f;
            atomicAdd(&s_conf[bin], conf);
            atomicAdd(&s_acc[bin], acc);
            atomicAdd(&s_cnt[bin], 1u);
        }
    }

    __syncthreads();
    if (t < N_BINS && s_cnt[t] != 0u) {
        atomicAdd(&conf_sum[t], (double)s_conf[t]);
        atomicAdd(&acc_sum[t], (double)s_acc[t]);
        atomicAdd(&counts[t], s_cnt[t]);
    }
}

// Pass 2: tiny scalar finish in f64.
__global__ void ece_pass2(const double* __restrict__ conf_sum,
                          const double* __restrict__ acc_sum,
                          const unsigned int* __restrict__ counts,
                          int n, float* __restrict__ out)
{
    double ece = 0.0;
    #pragma unroll
    for (int b = 0; b < N_BINS; ++b) {
        const unsigned int c = counts[b];
        if (c != 0u) {
            const double cd = (double)c;
            const double gap = fabs(conf_sum[b] / cd - acc_sum[b] / cd);
            ece += gap * cd / (double)n;
        }
    }
    out[0] = (float)ece;
}

extern "C" void kernel_launch(void* const* d_in, const int* in_sizes, int n_in,
                              void* d_out, int out_size, void* d_ws, size_t ws_size,
                              hipStream_t stream)
{
    const float* logits = (const float*)d_in[0];
    const int*   labels = (const int*)d_in[1];
    const int n = in_sizes[1];  // 1,000,000 rows

    double* conf_sum = (double*)d_ws;
    double* acc_sum  = conf_sum + N_BINS;
    unsigned int* counts = (unsigned int*)(acc_sum + N_BINS);

    hipMemsetAsync(d_ws, 0, N_BINS * (sizeof(double) * 2 + sizeof(unsigned int)),
                   stream);

    const int blocks = 2048;  // 8 blocks/CU at 256 thr -> exactly fills 256 CUs
    ece_pass1<<<blocks, 256, 0, stream>>>(logits, labels, n,
                                          conf_sum, acc_sum, counts);
    ece_pass2<<<1, 1, 0, stream>>>(conf_sum, acc_sum, counts, n, (float*)d_out);
}

// Round 3
// 143.124 us; speedup vs baseline: 1.9862x; 1.0213x over previous
//
#include <hip/hip_runtime.h>
#include <math.h>

#define N_BINS 15
#define NUM_CLASSES 128
#define LOG2E 1.4426950408889634f

// --- DPP helpers: full 16-lane butterfly with masks {1,2,7,15} ---
// xor1 = quad_perm[1,0,3,2] = 0xB1, xor2 = quad_perm[2,3,0,1] = 0x4E,
// xor7 = row_half_mirror = 0x141, xor15 = row_mirror = 0x140.
// span{1,2,7,15} = all 16 lanes -> every lane ends with the group reduction.
// Pure VALU (no LDS pipe), ~4 cyc/step vs ~25 for ds_swizzle.
template <int CTRL>
__device__ __forceinline__ float dpp_f(float x) {
    return __int_as_float(__builtin_amdgcn_update_dpp(
        0, __float_as_int(x), CTRL, 0xF, 0xF, true));
}
template <int CTRL>
__device__ __forceinline__ int dpp_i(int x) {
    return __builtin_amdgcn_update_dpp(0, x, CTRL, 0xF, 0xF, true);
}

__device__ __forceinline__ float rowmax16(float m) {
    m = fmaxf(m, dpp_f<0xB1>(m));
    m = fmaxf(m, dpp_f<0x4E>(m));
    m = fmaxf(m, dpp_f<0x141>(m));
    m = fmaxf(m, dpp_f<0x140>(m));
    return m;
}
__device__ __forceinline__ float rowsum16(float x) {
    x += dpp_f<0xB1>(x);
    x += dpp_f<0x4E>(x);
    x += dpp_f<0x141>(x);
    x += dpp_f<0x140>(x);
    return x;
}
__device__ __forceinline__ int rowmin16(int x) {
    x = min(x, dpp_i<0xB1>(x));
    x = min(x, dpp_i<0x4E>(x));
    x = min(x, dpp_i<0x141>(x));
    x = min(x, dpp_i<0x140>(x));
    return x;
}

// Process one row (held by a 16-lane group; lane holds cols 4s..4s+3 and
// 64+4s..64+4s+3). valid/lab only honored where s==0.
__device__ __forceinline__ void process_row(
    float4 ca, float4 cb, int s, int lab, bool valid,
    float* s_conf, float* s_acc, unsigned int* s_cnt)
{
    // local max: v_max3 tree (4 ops)
    const float t0 = fmaxf(fmaxf(ca.x, ca.y), ca.z);
    const float t1 = fmaxf(fmaxf(ca.w, cb.x), cb.y);
    const float t2 = fmaxf(fmaxf(cb.z, cb.w), t0);
    float m = fmaxf(t1, t2);
    m = rowmax16(m);                         // all 16 lanes get row max

    // sum(exp(v - m)) = sum(exp2(v*log2e - m*log2e)): fma + v_exp per elem
    const float nmL = -m * LOG2E;
    float e0 = __builtin_amdgcn_exp2f(fmaf(ca.x, LOG2E, nmL));
    float e1 = __builtin_amdgcn_exp2f(fmaf(ca.y, LOG2E, nmL));
    float e2 = __builtin_amdgcn_exp2f(fmaf(ca.z, LOG2E, nmL));
    float e3 = __builtin_amdgcn_exp2f(fmaf(ca.w, LOG2E, nmL));
    float e4 = __builtin_amdgcn_exp2f(fmaf(cb.x, LOG2E, nmL));
    float e5 = __builtin_amdgcn_exp2f(fmaf(cb.y, LOG2E, nmL));
    float e6 = __builtin_amdgcn_exp2f(fmaf(cb.z, LOG2E, nmL));
    float e7 = __builtin_amdgcn_exp2f(fmaf(cb.w, LOG2E, nmL));
    float e = ((e0 + e1) + (e2 + e3)) + ((e4 + e5) + (e6 + e7));
    e = rowsum16(e);

    // deferred argmax: per-element candidate, v_min3 tree, DPP min
    const int base = 4 * s;
    const int INF = 0x7FFFFFFF;
    const int c0 = (ca.x == m) ? base     : INF;
    const int c1 = (ca.y == m) ? base + 1 : INF;
    const int c2 = (ca.z == m) ? base + 2 : INF;
    const int c3 = (ca.w == m) ? base + 3 : INF;
    const int c4 = (cb.x == m) ? base + 64 : INF;
    const int c5 = (cb.y == m) ? base + 65 : INF;
    const int c6 = (cb.z == m) ? base + 66 : INF;
    const int c7 = (cb.w == m) ? base + 67 : INF;
    const int m1 = min(min(c0, c1), c2);
    const int m2 = min(min(c3, c4), c5);
    const int m3 = min(min(c6, c7), m1);
    int idx = min(m2, m3);
    idx = rowmin16(idx);                     // first-occurrence argmax

    if (valid && s == 0) {
        const float conf = __builtin_amdgcn_rcpf(e);  // 1 ulp; conf in (0,1]
        int bin = (int)ceilf(conf * (float)N_BINS) - 1;
        bin = min(max(bin, 0), N_BINS - 1);
        atomicAdd(&s_conf[bin], conf);
        atomicAdd(&s_acc[bin], (idx == lab) ? 1.0f : 0.0f);
        atomicAdd(&s_cnt[bin], 1u);
    }
}

// Pass 1: 16 lanes/row, 4 rows/wave/tile, 2 tiles per grid-stride iteration
// (8 rows), next iteration's tiles prefetched (64B/lane in flight).
__global__ __launch_bounds__(256) void ece_pass1(
    const float* __restrict__ logits,
    const int* __restrict__ labels,
    int n,
    double* __restrict__ conf_sum,
    double* __restrict__ acc_sum,
    unsigned int* __restrict__ counts)
{
    __shared__ float s_conf[N_BINS];
    __shared__ float s_acc[N_BINS];
    __shared__ unsigned int s_cnt[N_BINS];

    const int t = threadIdx.x;
    if (t < N_BINS) { s_conf[t] = 0.f; s_acc[t] = 0.f; s_cnt[t] = 0u; }
    __syncthreads();

    const int lane = t & 63;
    const int g    = lane >> 4;
    const int s    = lane & 15;
    const int wavesPerBlock = blockDim.x >> 6;
    const long long waveId = (long long)blockIdx.x * wavesPerBlock + (t >> 6);
    const long long nWaves = (long long)gridDim.x * wavesPerBlock;
    const long long rstride = nWaves * 8;

    long long base = waveId * 8;   // wave handles rows base..base+7 per iter

    float4 a0 = {0,0,0,0}, a1 = {0,0,0,0}, b0 = {0,0,0,0}, b1 = {0,0,0,0};
    {
        const long long rA = base + g, rB = rA + 4;
        if (rA < n) {
            const float4* __restrict__ p =
                (const float4*)(logits + rA * (long long)NUM_CLASSES);
            a0 = p[s]; a1 = p[s + 16];
        }
        if (rB < n) {
            const float4* __restrict__ p =
                (const float4*)(logits + rB * (long long)NUM_CLASSES);
            b0 = p[s]; b1 = p[s + 16];
        }
    }

    for (; base < n; base += rstride) {
        const long long rA = base + g, rB = rA + 4;
        const bool vA = rA < n, vB = rB < n;
        const int labA = vA ? labels[rA] : -1;   // issued early, group-uniform
        const int labB = vB ? labels[rB] : -1;

        // prefetch next grid-stride iteration
        float4 na0 = a0, na1 = a1, nb0 = b0, nb1 = b1;
        {
            const long long nA = rA + rstride, nB = nA + 4;
            if (nA < n) {
                const float4* __restrict__ p =
                    (const float4*)(logits + nA * (long long)NUM_CLASSES);
                na0 = p[s]; na1 = p[s + 16];
            }
            if (nB < n) {
                const float4* __restrict__ p =
                    (const float4*)(logits + nB * (long long)NUM_CLASSES);
                nb0 = p[s]; nb1 = p[s + 16];
            }
        }

        process_row(a0, a1, s, labA, vA, s_conf, s_acc, s_cnt);
        process_row(b0, b1, s, labB, vB, s_conf, s_acc, s_cnt);

        a0 = na0; a1 = na1; b0 = nb0; b1 = nb1;
    }

    __syncthreads();
    if (t < N_BINS && s_cnt[t] != 0u) {
        atomicAdd(&conf_sum[t], (double)s_conf[t]);
        atomicAdd(&acc_sum[t], (double)s_acc[t]);
        atomicAdd(&counts[t], s_cnt[t]);
    }
}

// Pass 2: tiny scalar finish in f64.
__global__ void ece_pass2(const double* __restrict__ conf_sum,
                          const double* __restrict__ acc_sum,
                          const unsigned int* __restrict__ counts,
                          int n, float* __restrict__ out)
{
    double ece = 0.0;
    #pragma unroll
    for (int b = 0; b < N_BINS; ++b) {
        const unsigned int c = counts[b];
        if (c != 0u) {
            const double cd = (double)c;
            const double gap = fabs(conf_sum[b] / cd - acc_sum[b] / cd);
            ece += gap * cd / (double)n;
        }
    }
    out[0] = (float)ece;
}

extern "C" void kernel_launch(void* const* d_in, const int* in_sizes, int n_in,
                              void* d_out, int out_size, void* d_ws, size_t ws_size,
                              hipStream_t stream)
{
    const float* logits = (const float*)d_in[0];
    const int*   labels = (const int*)d_in[1];
    const int n = in_sizes[1];  // 1,000,000 rows

    double* conf_sum = (double*)d_ws;
    double* acc_sum  = conf_sum + N_BINS;
    unsigned int* counts = (unsigned int*)(acc_sum + N_BINS);

    hipMemsetAsync(d_ws, 0, N_BINS * (sizeof(double) * 2 + sizeof(unsigned int)),
                   stream);

    const int blocks = 2048;  // 8 blocks/CU at 256 thr -> fills 256 CUs
    ece_pass1<<<blocks, 256, 0, stream>>>(logits, labels, n,
                                          conf_sum, acc_sum, counts);
    ece_pass2<<<1, 1, 0, stream>>>(conf_sum, acc_sum, counts, n, (float*)d_out);
}

// Round 4
// 127.048 us; speedup vs baseline: 2.2376x; 1.1265x over previous
//
#include <hip/hip_runtime.h>
#include <math.h>

#define N_BINS 15
#define NUM_CLASSES 128
#define LOG2E 1.4426950408889634f

// --- DPP helpers: full 16-lane butterfly with xor-span {1,2,7,15} ---
// 0xB1 = quad_perm[1,0,3,2] (xor1), 0x4E = quad_perm[2,3,0,1] (xor2),
// 0x141 = row_half_mirror (xor7), 0x140 = row_mirror (xor15).
template <int CTRL>
__device__ __forceinline__ float dpp_f(float x) {
    return __int_as_float(__builtin_amdgcn_update_dpp(
        0, __float_as_int(x), CTRL, 0xF, 0xF, true));
}
template <int CTRL>
__device__ __forceinline__ int dpp_i(int x) {
    return __builtin_amdgcn_update_dpp(0, x, CTRL, 0xF, 0xF, true);
}

__device__ __forceinline__ float rowmax16(float m) {
    m = fmaxf(m, dpp_f<0xB1>(m));
    m = fmaxf(m, dpp_f<0x4E>(m));
    m = fmaxf(m, dpp_f<0x141>(m));
    m = fmaxf(m, dpp_f<0x140>(m));
    return m;
}
__device__ __forceinline__ float rowsum16(float x) {
    x += dpp_f<0xB1>(x);
    x += dpp_f<0x4E>(x);
    x += dpp_f<0x141>(x);
    x += dpp_f<0x140>(x);
    return x;
}
__device__ __forceinline__ int rowmin16(int x) {
    x = min(x, dpp_i<0xB1>(x));
    x = min(x, dpp_i<0x4E>(x));
    x = min(x, dpp_i<0x141>(x));
    x = min(x, dpp_i<0x140>(x));
    return x;
}

// One row held by a 16-lane group; lane holds cols colbase..+3 and 64+colbase..+3.
__device__ __forceinline__ void process_row(
    float4 ca, float4 cb, int colbase, bool leader, int lab, bool valid,
    float* s_conf, float* s_acc, unsigned int* s_cnt)
{
    // row max: v_max3 tree + 4-step DPP
    const float t0 = fmaxf(fmaxf(ca.x, ca.y), ca.z);
    const float t1 = fmaxf(fmaxf(ca.w, cb.x), cb.y);
    const float t2 = fmaxf(fmaxf(cb.z, cb.w), t0);
    float m = fmaxf(t1, t2);
    m = rowmax16(m);

    // sum(exp2(v*log2e - m*log2e))
    const float nmL = -m * LOG2E;
    float e0 = __builtin_amdgcn_exp2f(fmaf(ca.x, LOG2E, nmL));
    float e1 = __builtin_amdgcn_exp2f(fmaf(ca.y, LOG2E, nmL));
    float e2 = __builtin_amdgcn_exp2f(fmaf(ca.z, LOG2E, nmL));
    float e3 = __builtin_amdgcn_exp2f(fmaf(ca.w, LOG2E, nmL));
    float e4 = __builtin_amdgcn_exp2f(fmaf(cb.x, LOG2E, nmL));
    float e5 = __builtin_amdgcn_exp2f(fmaf(cb.y, LOG2E, nmL));
    float e6 = __builtin_amdgcn_exp2f(fmaf(cb.z, LOG2E, nmL));
    float e7 = __builtin_amdgcn_exp2f(fmaf(cb.w, LOG2E, nmL));
    float e = ((e0 + e1) + (e2 + e3)) + ((e4 + e5) + (e6 + e7));
    e = rowsum16(e);

    // deferred argmax (first occurrence): candidate index or INF, min-reduce
    const int INF = 0x7FFFFFFF;
    const int c0 = (ca.x == m) ? colbase      : INF;
    const int c1 = (ca.y == m) ? colbase + 1  : INF;
    const int c2 = (ca.z == m) ? colbase + 2  : INF;
    const int c3 = (ca.w == m) ? colbase + 3  : INF;
    const int c4 = (cb.x == m) ? colbase + 64 : INF;
    const int c5 = (cb.y == m) ? colbase + 65 : INF;
    const int c6 = (cb.z == m) ? colbase + 66 : INF;
    const int c7 = (cb.w == m) ? colbase + 67 : INF;
    const int m1 = min(min(c0, c1), c2);
    const int m2 = min(min(c3, c4), c5);
    const int m3 = min(min(c6, c7), m1);
    int idx = min(m2, m3);
    idx = rowmin16(idx);

    if (valid && leader) {
        const float conf = __builtin_amdgcn_rcpf(e);
        int bin = (int)ceilf(conf * (float)N_BINS) - 1;
        bin = min(max(bin, 0), N_BINS - 1);
        atomicAdd(&s_conf[bin], conf);
        atomicAdd(&s_acc[bin], (idx == lab) ? 1.0f : 0.0f);
        atomicAdd(&s_cnt[bin], 1u);
    }
}

// Pass 1: 16 lanes/row, two 4-row tiles (8 rows) per wave per iteration,
// depth-1 prefetch. All addressing is incremental u32 byte offsets
// (n*512 < 2^32); main loop is branch-free (per-wave exact full-iteration
// count, single generic guarded tail).
__global__ __launch_bounds__(256) void ece_pass1(
    const float* __restrict__ logits,
    const int* __restrict__ labels,
    int n,
    double* __restrict__ conf_sum,
    double* __restrict__ acc_sum,
    unsigned int* __restrict__ counts)
{
    __shared__ float s_conf[N_BINS];
    __shared__ float s_acc[N_BINS];
    __shared__ unsigned int s_cnt[N_BINS];

    const int t = threadIdx.x;
    if (t < N_BINS) { s_conf[t] = 0.f; s_acc[t] = 0.f; s_cnt[t] = 0u; }
    __syncthreads();

    const int lane = t & 63;
    const int g    = lane >> 4;          // row within 4-row tile
    const int s    = lane & 15;          // sublane within 16-lane group
    const bool leader = (s == 0);
    const int colbase = 4 * s;

    const int wid = (blockIdx.x << 2) | (t >> 6);   // wave id
    const int nw  = gridDim.x << 2;                 // total waves
    const unsigned rstep = (unsigned)nw * 8u;       // rows per grid iteration
    const unsigned bstep = rstep * 512u;            // bytes per grid iteration

    // iterations where ALL 8 rows of this wave are < n
    int nfull = 0;
    {
        const int lim = n - 8 - wid * 8;
        if (lim >= 0) nfull = lim / (int)rstep + 1;
    }

    const char* __restrict__ Lg = (const char*)logits;
    const unsigned row0 = (unsigned)(wid * 8 + g);      // tile-A row, iter 0
    unsigned off  = row0 * 512u + (unsigned)s * 16u;    // tile-A byte offset
    unsigned lrow = row0;                               // label index

    float4 a0, a1, b0, b1;
    if (nfull > 0) {
        a0 = *(const float4*)(Lg + off);
        a1 = *(const float4*)(Lg + off + 256u);
        b0 = *(const float4*)(Lg + off + 2048u);
        b1 = *(const float4*)(Lg + off + 2304u);
    }

    for (int k = 0; k < nfull; ++k) {
        const int labA = labels[lrow];
        const int labB = labels[lrow + 4u];
        const float4 ca0 = a0, ca1 = a1, cb0 = b0, cb1 = b1;

        const unsigned noff = off + bstep;
        if (k + 1 < nfull) {   // wave-uniform scalar branch
            a0 = *(const float4*)(Lg + noff);
            a1 = *(const float4*)(Lg + noff + 256u);
            b0 = *(const float4*)(Lg + noff + 2048u);
            b1 = *(const float4*)(Lg + noff + 2304u);
        }

        process_row(ca0, ca1, colbase, leader, labA, true, s_conf, s_acc, s_cnt);
        process_row(cb0, cb1, colbase, leader, labB, true, s_conf, s_acc, s_cnt);

        off = noff;
        lrow += rstep;
    }

    // generic guarded tail (at most one iteration; empty for n = 1e6)
    {
        const unsigned tbase = (unsigned)(wid * 8) + (unsigned)nfull * rstep;
        if (tbase < (unsigned)n) {
            const unsigned rA = tbase + (unsigned)g;
            const unsigned rB = rA + 4u;
            const bool vA = rA < (unsigned)n;
            const bool vB = rB < (unsigned)n;
            const unsigned cA = vA ? rA : (unsigned)(n - 1);
            const unsigned cB = vB ? rB : (unsigned)(n - 1);
            const unsigned oA = cA * 512u + (unsigned)s * 16u;
            const unsigned oB = cB * 512u + (unsigned)s * 16u;
            float4 ta0 = *(const float4*)(Lg + oA);
            float4 ta1 = *(const float4*)(Lg + oA + 256u);
            float4 tb0 = *(const float4*)(Lg + oB);
            float4 tb1 = *(const float4*)(Lg + oB + 256u);
            const int labA = vA ? labels[rA] : -1;
            const int labB = vB ? labels[rB] : -1;
            process_row(ta0, ta1, colbase, leader, labA, vA, s_conf, s_acc, s_cnt);
            process_row(tb0, tb1, colbase, leader, labB, vB, s_conf, s_acc, s_cnt);
        }
    }

    __syncthreads();
    if (t < N_BINS && s_cnt[t] != 0u) {
        atomicAdd(&conf_sum[t], (double)s_conf[t]);
        atomicAdd(&acc_sum[t], (double)s_acc[t]);
        atomicAdd(&counts[t], s_cnt[t]);
    }
}

// Pass 2: tiny scalar finish in f64.
__global__ void ece_pass2(const double* __restrict__ conf_sum,
                          const double* __restrict__ acc_sum,
                          const unsigned int* __restrict__ counts,
                          int n, float* __restrict__ out)
{
    double ece = 0.0;
    #pragma unroll
    for (int b = 0; b < N_BINS; ++b) {
        const unsigned int c = counts[b];
        if (c != 0u) {
            const double cd = (double)c;
            const double gap = fabs(conf_sum[b] / cd - acc_sum[b] / cd);
            ece += gap * cd / (double)n;
        }
    }
    out[0] = (float)ece;
}

extern "C" void kernel_launch(void* const* d_in, const int* in_sizes, int n_in,
                              void* d_out, int out_size, void* d_ws, size_t ws_size,
                              hipStream_t stream)
{
    const float* logits = (const float*)d_in[0];
    const int*   labels = (const int*)d_in[1];
    const int n = in_sizes[1];  // 1,000,000 rows

    double* conf_sum = (double*)d_ws;
    double* acc_sum  = conf_sum + N_BINS;
    unsigned int* counts = (unsigned int*)(acc_sum + N_BINS);

    hipMemsetAsync(d_ws, 0, N_BINS * (sizeof(double) * 2 + sizeof(unsigned int)),
                   stream);

    const int blocks = 2048;  // 8 blocks/CU at 256 thr
    ece_pass1<<<blocks, 256, 0, stream>>>(logits, labels, n,
                                          conf_sum, acc_sum, counts);
    ece_pass2<<<1, 1, 0, stream>>>(conf_sum, acc_sum, counts, n, (float*)d_out);
}